// Round 12
// baseline (769557.861 us; speedup 1.0000x reference)
//
#include <hip/hip_runtime.h>
#include <cstdint>
#include <cstddef>

#define T_STEPS 200
#define B_SZ    256
#define I_SZ    784
#define H_SZ    1000
#define O_SZ    10
#define M_ROWS  (T_STEPS * B_SZ)   // 51200

#define KT        25               // K padded 784 -> 800, 25 tiles of 32
#define TILE_WORDS 4096            // 32 k x 128 cols (floats)
#define MBLKS     400
#define NBLKS     8

typedef int int32x4 __attribute__((ext_vector_type(4)));

// granule (4-float) swizzle within a 128-word k-row; inverse for pack.
__device__ __forceinline__ int swz32(int g) { return (g & 24) | ((g + (g >> 3)) & 7); }
__device__ __forceinline__ int inv32(int p) { return (p & 24) | ((p - (p >> 3)) & 7); }

typedef const __attribute__((address_space(1))) void gvoid;
typedef __attribute__((address_space(3))) void lvoid;
__device__ __forceinline__ void gload16(const void* g, void* l) {
    __builtin_amdgcn_global_load_lds((gvoid*)g, (lvoid*)l, 16, 0, 0);
}

// ---------------------------------------------------------------------------
// pack: src [nrows x 784] -> [blk128][kt][32k][128 words, granule swz32].
// ---------------------------------------------------------------------------
__global__ __launch_bounds__(256) void pack_kernel(
    const float* __restrict__ src, float* __restrict__ dst, int nrows)
{
    int bid = blockIdx.x;
    int blk = bid / KT, kt = bid - blk * KT;

    __shared__ float T[32 * 132];
    const int tid = threadIdx.x;

    #pragma unroll
    for (int it = 0; it < 4; ++it) {
        int id = tid + it * 256;
        int r  = id >> 3;
        int c4 = id & 7;
        int row = blk * 128 + r;
        int k   = kt * 32 + c4 * 4;
        float4 v = make_float4(0.f, 0.f, 0.f, 0.f);
        if (row < nrows && k < I_SZ)
            v = *(const float4*)(src + (size_t)row * I_SZ + k);
        T[(c4*4 + 0) * 132 + r] = v.x;
        T[(c4*4 + 1) * 132 + r] = v.y;
        T[(c4*4 + 2) * 132 + r] = v.z;
        T[(c4*4 + 3) * 132 + r] = v.w;
    }
    __syncthreads();

    float* out = dst + (size_t)(blk * KT + kt) * TILE_WORDS;
    #pragma unroll
    for (int it = 0; it < 4; ++it) {
        int id = tid + it * 256;
        int k  = id >> 5;
        int pg = id & 31;
        int g  = inv32(pg);
        float4 v = *(const float4*)&T[k * 132 + g * 4];
        *(float4*)(out + k * 128 + pg * 4) = v;
    }
}

// ---------------------------------------------------------------------------
// GEMM1 v6 (shipping path, proven 950 us, absmax 0.0) — UNCHANGED.
// ---------------------------------------------------------------------------
__global__ __launch_bounds__(256, 4) void gemm1_v6(
    const float* __restrict__ Xp, const float* __restrict__ Wp,
    const float* __restrict__ b_ih, const float* __restrict__ b_hh,
    float* __restrict__ Z)
{
    __shared__ float Al[TILE_WORDS];
    __shared__ float Bl[TILE_WORDS];

    const int tid = threadIdx.x;
    const int tr  = tid >> 4;
    const int tc  = tid & 15;

    int bid  = blockIdx.x;
    int wg   = (bid & 7) * 400 + (bid >> 3);
    int mblk = wg >> 3;
    int nblk = wg & 7;
    const int row0 = mblk * 128;
    const int col0 = nblk * 128;

    const int a0 = swz32(2*tr)     * 4;
    const int a1 = swz32(2*tr + 1) * 4;
    const int b0 = swz32(2*tc)     * 4;
    const int b1 = swz32(2*tc + 1) * 4;

    const float* pA = Xp + (size_t)mblk * KT * TILE_WORDS;
    const float* pB = Wp + (size_t)nblk * KT * TILE_WORDS;

    float acc[8][8] = {};

    for (int kt = 0; kt < KT; ++kt) {
        const float* sA = pA + kt * TILE_WORDS + tid * 4;
        const float* sB = pB + kt * TILE_WORDS + tid * 4;
        gload16(sA,        &Al[        tid * 4]);
        gload16(sA + 1024, &Al[1024 + tid * 4]);
        gload16(sA + 2048, &Al[2048 + tid * 4]);
        gload16(sA + 3072, &Al[3072 + tid * 4]);
        gload16(sB,        &Bl[        tid * 4]);
        gload16(sB + 1024, &Bl[1024 + tid * 4]);
        gload16(sB + 2048, &Bl[2048 + tid * 4]);
        gload16(sB + 3072, &Bl[3072 + tid * 4]);
        __syncthreads();

        #pragma unroll
        for (int k = 0; k < 32; ++k) {
            const float4 A0 = *(const float4*)&Al[k*128 + a0];
            const float4 A1 = *(const float4*)&Al[k*128 + a1];
            const float4 B0 = *(const float4*)&Bl[k*128 + b0];
            const float4 B1 = *(const float4*)&Bl[k*128 + b1];
            #define FMA_ROW(i, av) \
                acc[i][0] = fmaf(av, B0.x, acc[i][0]); \
                acc[i][1] = fmaf(av, B0.y, acc[i][1]); \
                acc[i][2] = fmaf(av, B0.z, acc[i][2]); \
                acc[i][3] = fmaf(av, B0.w, acc[i][3]); \
                acc[i][4] = fmaf(av, B1.x, acc[i][4]); \
                acc[i][5] = fmaf(av, B1.y, acc[i][5]); \
                acc[i][6] = fmaf(av, B1.z, acc[i][6]); \
                acc[i][7] = fmaf(av, B1.w, acc[i][7]);
            FMA_ROW(0, A0.x) FMA_ROW(1, A0.y) FMA_ROW(2, A0.z) FMA_ROW(3, A0.w)
            FMA_ROW(4, A1.x) FMA_ROW(5, A1.y) FMA_ROW(6, A1.z) FMA_ROW(7, A1.w)
            #undef FMA_ROW
        }
        __syncthreads();
    }

    float bias[8];
    #pragma unroll
    for (int j = 0; j < 8; ++j) {
        int cc = col0 + tc * 8 + j;
        bias[j] = (cc < H_SZ) ? (b_ih[cc] + b_hh[cc]) : 0.f;
    }

    const bool full = (col0 + 127 < H_SZ);
    #pragma unroll
    for (int i = 0; i < 8; ++i) {
        int rr = row0 + tr * 8 + i;
        float* zrow = Z + (size_t)rr * H_SZ + col0 + tc * 8;
        if (full) {
            float4 v0 = make_float4(acc[i][0] + bias[0], acc[i][1] + bias[1],
                                    acc[i][2] + bias[2], acc[i][3] + bias[3]);
            float4 v1 = make_float4(acc[i][4] + bias[4], acc[i][5] + bias[5],
                                    acc[i][6] + bias[6], acc[i][7] + bias[7]);
            *(float4*)(zrow + 0) = v0;
            *(float4*)(zrow + 4) = v1;
        } else {
            #pragma unroll
            for (int j = 0; j < 8; ++j) {
                int cc = col0 + tc * 8 + j;
                if (cc < H_SZ) zrow[j] = acc[i][j] + bias[j];
            }
        }
    }
}

// ---------------------------------------------------------------------------
// i8-digit MFMA probe: EXACT fixed-point GEMM via v_mfma_i32_16x16x64_i8.
// x -> rne(x*2^18), 3 base-128 signed digits; W -> rne(w*2^21), 3 digits.
// 9 products grouped by weight into 5 exact i32 accumulators; double combine.
// Subset 256 rows x 128 cols, compared vs fp32 z1. Inline asm (isa-doc
// operand shapes: A,B = 4 VGPR; C/D = 4) to avoid builtin-signature risk.
// ---------------------------------------------------------------------------
__global__ void zero_ctr_kernel(int* c) {
    if (threadIdx.x < 4) c[threadIdx.x] = 0;
}

__device__ __forceinline__ int32x4 mfma_i8(int32x4 a, int32x4 b, int32x4 c) {
    asm("v_mfma_i32_16x16x64_i8 %0, %1, %2, %0" : "+v"(c) : "v"(a), "v"(b));
    return c;
}

__global__ __launch_bounds__(64) void diag_i8(
    const float* __restrict__ x, const float* __restrict__ W,
    const float* __restrict__ bih, const float* __restrict__ bhh,
    const float* __restrict__ z1, int* __restrict__ ctr)
{
    const int tile = blockIdx.x;      // 0..127
    const int tR   = tile >> 3;       // 0..15
    const int tC   = tile & 7;        // 0..7
    const int lane = threadIdx.x;
    const int arow = tR * 16 + (lane & 15);
    const int bcol = tC * 16 + (lane & 15);
    const int kb   = (lane >> 4) * 16;

    int32x4 s0 = {}, s1 = {}, s2 = {}, s3 = {}, s4 = {};

    for (int kk = 0; kk < 13; ++kk) {   // 13*64 = 832 >= 784 (zero-padded)
        unsigned pa2[4] = {}, pa1[4] = {}, pa0[4] = {};
        unsigned pb2[4] = {}, pb1[4] = {}, pb0[4] = {};
        #pragma unroll
        for (int j = 0; j < 16; ++j) {
            int k = kk * 64 + kb + j;
            float xv = (k < I_SZ) ? x[(size_t)arow * I_SZ + k] : 0.f;
            float wv = (k < I_SZ) ? W[(size_t)bcol * I_SZ + k] : 0.f;
            int X = __float2int_rn(xv * 262144.0f);     // 2^18, |X| <= 1.47e6
            int x2 = (X + 8192) >> 14; int rA = X - (x2 << 14);
            int x1 = (rA + 64) >> 7;   int x0 = rA - (x1 << 7);
            int Wq = __float2int_rn(wv * 2097152.0f);   // 2^21, |Wq| <= 4.2e5
            int w2 = (Wq + 8192) >> 14; int rB = Wq - (w2 << 14);
            int w1 = (rB + 64) >> 7;    int w0 = rB - (w1 << 7);
            const int sh = (j & 3) * 8, wd = j >> 2;
            pa2[wd] |= ((unsigned)(unsigned char)(signed char)x2) << sh;
            pa1[wd] |= ((unsigned)(unsigned char)(signed char)x1) << sh;
            pa0[wd] |= ((unsigned)(unsigned char)(signed char)x0) << sh;
            pb2[wd] |= ((unsigned)(unsigned char)(signed char)w2) << sh;
            pb1[wd] |= ((unsigned)(unsigned char)(signed char)w1) << sh;
            pb0[wd] |= ((unsigned)(unsigned char)(signed char)w0) << sh;
        }
        int32x4 A2 = {(int)pa2[0], (int)pa2[1], (int)pa2[2], (int)pa2[3]};
        int32x4 A1 = {(int)pa1[0], (int)pa1[1], (int)pa1[2], (int)pa1[3]};
        int32x4 A0 = {(int)pa0[0], (int)pa0[1], (int)pa0[2], (int)pa0[3]};
        int32x4 B2 = {(int)pb2[0], (int)pb2[1], (int)pb2[2], (int)pb2[3]};
        int32x4 B1 = {(int)pb1[0], (int)pb1[1], (int)pb1[2], (int)pb1[3]};
        int32x4 B0 = {(int)pb0[0], (int)pb0[1], (int)pb0[2], (int)pb0[3]};

        s4 = mfma_i8(A2, B2, s4);                               // weight 2^28
        s3 = mfma_i8(A2, B1, s3); s3 = mfma_i8(A1, B2, s3);     // 2^21
        s2 = mfma_i8(A2, B0, s2); s2 = mfma_i8(A1, B1, s2);
        s2 = mfma_i8(A0, B2, s2);                               // 2^14
        s1 = mfma_i8(A1, B0, s1); s1 = mfma_i8(A0, B1, s1);     // 2^7
        s0 = mfma_i8(A0, B0, s0);                               // 2^0
    }

    double bias = (double)bih[bcol] + (double)bhh[bcol];
    #pragma unroll
    for (int r = 0; r < 4; ++r) {
        int orow = tR * 16 + (lane >> 4) * 4 + r;   // m89 C/D layout
        double zq = ((double)s4[r] * 268435456.0 + (double)s3[r] * 2097152.0
                   + (double)s2[r] * 16384.0     + (double)s1[r] * 128.0
                   + (double)s0[r]) * (1.0 / 549755813888.0);   // * 2^-39
        float zv = z1[(size_t)orow * H_SZ + bcol];
        float d  = fabsf((float)(zq + bias) - zv);
        if (d > 5e-5f) atomicAdd(&ctr[0], 1);
        if (d > 5e-4f) atomicAdd(&ctr[1], 1);
        if (d > 5e-3f) atomicAdd(&ctr[2], 1);
    }
}

// verdict in duration; levels 4x apart (r5/r10 calibration: ~6-8 cyc/iter).
// u=2 (~2ms): EXACT, ship i8 | u=8: quant tail | u=32: >5e-4 | u=128: layout
__global__ void diag_spin(const int* __restrict__ c) {
    int u;
    if      (c[2] > 0) u = 128;
    else if (c[1] > 0) u = 32;
    else if (c[0] > 0) u = 8;
    else               u = 2;
    float a = 1.0f;
    long n = (long)u * 300000L;
    for (long i = 0; i < n; ++i)
        asm volatile("v_fmac_f32 %0, %1, %2" : "+v"(a) : "v"(1.000001f), "v"(1e-30f));
}

// ---------------------------------------------------------------------------
// Scan1 / GEMM2 / Scan2 (proven)
// ---------------------------------------------------------------------------
__global__ __launch_bounds__(256) void scan1_kernel(
    float* __restrict__ Z, const float* __restrict__ beta)
{
    int idx = blockIdx.x * blockDim.x + threadIdx.x;
    if (idx >= B_SZ * H_SZ) return;
    int h = idx % H_SZ;
    float be = fminf(fmaxf(beta[h], 0.f), 1.f);
    float hm = 0.f;
    const size_t stride = (size_t)B_SZ * H_SZ;
    float* p = Z + idx;
    for (int t = 0; t < T_STEPS; ++t) {
        float v = p[(size_t)t * stride];
        hm = fmaxf(fmaf(be, hm, v), 0.f);
        p[(size_t)t * stride] = (hm > 1.0f) ? 1.0f : 0.0f;
    }
}

__global__ __launch_bounds__(256) void gemm2_kernel(
    const float* __restrict__ S, const float* __restrict__ W2,
    const float* __restrict__ b_ih2, const float* __restrict__ b_hh2,
    float* __restrict__ Z2)
{
    __shared__ float W2s[O_SZ * H_SZ];
    for (int i = threadIdx.x; i < O_SZ * H_SZ; i += blockDim.x)
        W2s[i] = W2[i];
    __syncthreads();

    const int wave  = threadIdx.x >> 6;
    const int lane  = threadIdx.x & 63;
    const int wgid  = blockIdx.x * (blockDim.x >> 6) + wave;
    const int nwave = gridDim.x * (blockDim.x >> 6);

    for (int m = wgid; m < M_ROWS; m += nwave) {
        const float* row = S + (size_t)m * H_SZ;
        float acc[O_SZ];
        #pragma unroll
        for (int o = 0; o < O_SZ; ++o) acc[o] = 0.f;

        for (int h = lane; h < H_SZ; h += 64) {
            float s = row[h];
            #pragma unroll
            for (int o = 0; o < O_SZ; ++o)
                acc[o] = fmaf(s, W2s[o * H_SZ + h], acc[o]);
        }
        #pragma unroll
        for (int o = 0; o < O_SZ; ++o) {
            float v = acc[o];
            #pragma unroll
            for (int off = 32; off > 0; off >>= 1)
                v += __shfl_down(v, off, 64);
            if (lane == 0)
                Z2[(size_t)m * O_SZ + o] = v + b_ih2[o] + b_hh2[o];
        }
    }
}

#define CH 20
__global__ __launch_bounds__(256) void scan2_kernel(
    float* __restrict__ Z2io, const float* __restrict__ beta2)
{
    int idx = blockIdx.x * blockDim.x + threadIdx.x;
    if (idx >= B_SZ * O_SZ) return;
    int o = idx % O_SZ;
    float be = fminf(fmaxf(beta2[o], 0.f), 1.f);
    float hm = 0.f;
    const int stride = B_SZ * O_SZ;
    for (int t0 = 0; t0 < T_STEPS; t0 += CH) {
        float v[CH];
        #pragma unroll
        for (int i = 0; i < CH; ++i)
            v[i] = Z2io[(size_t)(t0 + i) * stride + idx];
        #pragma unroll
        for (int i = 0; i < CH; ++i) {
            hm = fmaxf(fmaf(be, hm, v[i]), 0.f);
            Z2io[(size_t)(t0 + i) * stride + idx] = (hm > 1.0f) ? 1.0f : 0.0f;
        }
    }
}

// ---------------------------------------------------------------------------
extern "C" void kernel_launch(void* const* d_in, const int* in_sizes, int n_in,
                              void* d_out, int out_size, void* d_ws, size_t ws_size,
                              hipStream_t stream)
{
    const float* x     = (const float*)d_in[0];
    const float* W1    = (const float*)d_in[1];
    const float* bih1  = (const float*)d_in[2];
    const float* bhh1  = (const float*)d_in[3];
    const float* beta1 = (const float*)d_in[4];
    const float* W2    = (const float*)d_in[5];
    const float* bih2  = (const float*)d_in[6];
    const float* bhh2  = (const float*)d_in[7];
    const float* beta2 = (const float*)d_in[8];
    float* out = (float*)d_out;

    // z1 (204.8 MB) + Xp (163.84 MB) + Wp (3.28 MB) + ctr (16 B)
    char* base = (char*)d_ws;
    float* z1 = (float*)base;
    float* Xp = (float*)(base + (size_t)M_ROWS * H_SZ * 4);
    float* Wp = Xp + (size_t)MBLKS * KT * TILE_WORDS;
    int*   ctr = (int*)(Wp + (size_t)NBLKS * KT * TILE_WORDS);

    pack_kernel<<<MBLKS * KT, 256, 0, stream>>>(x,  Xp, M_ROWS);
    pack_kernel<<<NBLKS * KT, 256, 0, stream>>>(W1, Wp, H_SZ);
    zero_ctr_kernel<<<1, 64, 0, stream>>>(ctr);

    gemm1_v6<<<MBLKS * NBLKS, 256, 0, stream>>>(Xp, Wp, bih1, bhh1, z1);

    // i8-digit probe (reads z1 BEFORE scan1 overwrites it in place)
    diag_i8<<<128, 64, 0, stream>>>(x, W1, bih1, bhh1, z1, ctr);
    diag_spin<<<1, 64, 0, stream>>>(ctr);

    scan1_kernel<<<(B_SZ * H_SZ) / 256, 256, 0, stream>>>(z1, beta1);
    gemm2_kernel<<<2048, 256, 0, stream>>>(z1, W2, bih2, bhh2, out);
    scan2_kernel<<<(B_SZ * O_SZ + 255) / 256, 256, 0, stream>>>(out, beta2);
}

// Round 13
// 1150.835 us; speedup vs baseline: 668.6950x; 668.6950x over previous
//
#include <hip/hip_runtime.h>
#include <cstdint>
#include <cstddef>

#define T_STEPS 200
#define B_SZ    256
#define I_SZ    784
#define H_SZ    1000
#define O_SZ    10
#define M_ROWS  (T_STEPS * B_SZ)   // 51200

#define KT        25               // K padded 784 -> 800, 25 tiles of 32
#define TILE_WORDS 4096            // 32 k x 128 cols (floats)
#define MBLKS     400
#define NBLKS     8

// granule (4-float) swizzle within a 128-word k-row; inverse for pack.
__device__ __forceinline__ int swz32(int g) { return (g & 24) | ((g + (g >> 3)) & 7); }
__device__ __forceinline__ int inv32(int p) { return (p & 24) | ((p - (p >> 3)) & 7); }

typedef const __attribute__((address_space(1))) void gvoid;
typedef __attribute__((address_space(3))) void lvoid;
__device__ __forceinline__ void gload16(const void* g, void* l) {
    __builtin_amdgcn_global_load_lds((gvoid*)g, (lvoid*)l, 16, 0, 0);
}

// ---------------------------------------------------------------------------
// pack: src [nrows x 784] -> [blk128][kt][32k][128 words, granule swz32].
// ---------------------------------------------------------------------------
__global__ __launch_bounds__(256) void pack_kernel(
    const float* __restrict__ src, float* __restrict__ dst, int nrows)
{
    int bid = blockIdx.x;
    int blk = bid / KT, kt = bid - blk * KT;

    __shared__ float T[32 * 132];
    const int tid = threadIdx.x;

    #pragma unroll
    for (int it = 0; it < 4; ++it) {
        int id = tid + it * 256;
        int r  = id >> 3;
        int c4 = id & 7;
        int row = blk * 128 + r;
        int k   = kt * 32 + c4 * 4;
        float4 v = make_float4(0.f, 0.f, 0.f, 0.f);
        if (row < nrows && k < I_SZ)
            v = *(const float4*)(src + (size_t)row * I_SZ + k);
        T[(c4*4 + 0) * 132 + r] = v.x;
        T[(c4*4 + 1) * 132 + r] = v.y;
        T[(c4*4 + 2) * 132 + r] = v.z;
        T[(c4*4 + 3) * 132 + r] = v.w;
    }
    __syncthreads();

    float* out = dst + (size_t)(blk * KT + kt) * TILE_WORDS;
    #pragma unroll
    for (int it = 0; it < 4; ++it) {
        int id = tid + it * 256;
        int k  = id >> 5;
        int pg = id & 31;
        int g  = inv32(pg);
        float4 v = *(const float4*)&T[k * 132 + g * 4];
        *(float4*)(out + k * 128 + pg * 4) = v;
    }
}

// ---------------------------------------------------------------------------
// GEMM1 v6: fp32 VALU. MFMA path closed for good: r5 (f16-split), r10
// (bf16x3), r12 (i8-digit, mathematically-exact arithmetic) all failed
// their accuracy probes -> the one remaining unknown is MFMA operand
// layout detail not worth more rounds; binary-spike output needs fp32.
// 88.3 TF = 86% of the m07-measured 103 TF FMA ceiling; VALUBusy ~80%,
// residual is the barrier/stage drain (m99-m141: structural at HIP level).
// ---------------------------------------------------------------------------
__global__ __launch_bounds__(256, 4) void gemm1_v6(
    const float* __restrict__ Xp, const float* __restrict__ Wp,
    const float* __restrict__ b_ih, const float* __restrict__ b_hh,
    float* __restrict__ Z)
{
    __shared__ float Al[TILE_WORDS];
    __shared__ float Bl[TILE_WORDS];

    const int tid = threadIdx.x;
    const int tr  = tid >> 4;
    const int tc  = tid & 15;

    int bid  = blockIdx.x;
    int wg   = (bid & 7) * 400 + (bid >> 3);
    int mblk = wg >> 3;
    int nblk = wg & 7;
    const int row0 = mblk * 128;
    const int col0 = nblk * 128;

    const int a0 = swz32(2*tr)     * 4;
    const int a1 = swz32(2*tr + 1) * 4;
    const int b0 = swz32(2*tc)     * 4;
    const int b1 = swz32(2*tc + 1) * 4;

    const float* pA = Xp + (size_t)mblk * KT * TILE_WORDS;
    const float* pB = Wp + (size_t)nblk * KT * TILE_WORDS;

    float acc[8][8] = {};

    for (int kt = 0; kt < KT; ++kt) {
        const float* sA = pA + kt * TILE_WORDS + tid * 4;
        const float* sB = pB + kt * TILE_WORDS + tid * 4;
        gload16(sA,        &Al[        tid * 4]);
        gload16(sA + 1024, &Al[1024 + tid * 4]);
        gload16(sA + 2048, &Al[2048 + tid * 4]);
        gload16(sA + 3072, &Al[3072 + tid * 4]);
        gload16(sB,        &Bl[        tid * 4]);
        gload16(sB + 1024, &Bl[1024 + tid * 4]);
        gload16(sB + 2048, &Bl[2048 + tid * 4]);
        gload16(sB + 3072, &Bl[3072 + tid * 4]);
        __syncthreads();

        #pragma unroll
        for (int k = 0; k < 32; ++k) {
            const float4 A0 = *(const float4*)&Al[k*128 + a0];
            const float4 A1 = *(const float4*)&Al[k*128 + a1];
            const float4 B0 = *(const float4*)&Bl[k*128 + b0];
            const float4 B1 = *(const float4*)&Bl[k*128 + b1];
            #define FMA_ROW(i, av) \
                acc[i][0] = fmaf(av, B0.x, acc[i][0]); \
                acc[i][1] = fmaf(av, B0.y, acc[i][1]); \
                acc[i][2] = fmaf(av, B0.z, acc[i][2]); \
                acc[i][3] = fmaf(av, B0.w, acc[i][3]); \
                acc[i][4] = fmaf(av, B1.x, acc[i][4]); \
                acc[i][5] = fmaf(av, B1.y, acc[i][5]); \
                acc[i][6] = fmaf(av, B1.z, acc[i][6]); \
                acc[i][7] = fmaf(av, B1.w, acc[i][7]);
            FMA_ROW(0, A0.x) FMA_ROW(1, A0.y) FMA_ROW(2, A0.z) FMA_ROW(3, A0.w)
            FMA_ROW(4, A1.x) FMA_ROW(5, A1.y) FMA_ROW(6, A1.z) FMA_ROW(7, A1.w)
            #undef FMA_ROW
        }
        __syncthreads();
    }

    float bias[8];
    #pragma unroll
    for (int j = 0; j < 8; ++j) {
        int cc = col0 + tc * 8 + j;
        bias[j] = (cc < H_SZ) ? (b_ih[cc] + b_hh[cc]) : 0.f;
    }

    const bool full = (col0 + 127 < H_SZ);
    #pragma unroll
    for (int i = 0; i < 8; ++i) {
        int rr = row0 + tr * 8 + i;
        float* zrow = Z + (size_t)rr * H_SZ + col0 + tc * 8;
        if (full) {
            float4 v0 = make_float4(acc[i][0] + bias[0], acc[i][1] + bias[1],
                                    acc[i][2] + bias[2], acc[i][3] + bias[3]);
            float4 v1 = make_float4(acc[i][4] + bias[4], acc[i][5] + bias[5],
                                    acc[i][6] + bias[6], acc[i][7] + bias[7]);
            *(float4*)(zrow + 0) = v0;
            *(float4*)(zrow + 4) = v1;
        } else {
            #pragma unroll
            for (int j = 0; j < 8; ++j) {
                int cc = col0 + tc * 8 + j;
                if (cc < H_SZ) zrow[j] = acc[i][j] + bias[j];
            }
        }
    }
}

// ---------------------------------------------------------------------------
// Scan1: per (b,h) chain over t. Reads z1 floats; writes BYTE spikes
// (0/1) to S — identical arithmetic to the proven in-place version.
// ---------------------------------------------------------------------------
__global__ __launch_bounds__(256) void scan1_kernel(
    const float* __restrict__ Z, unsigned char* __restrict__ S,
    const float* __restrict__ beta)
{
    int idx = blockIdx.x * blockDim.x + threadIdx.x;
    if (idx >= B_SZ * H_SZ) return;
    int h = idx % H_SZ;
    float be = fminf(fmaxf(beta[h], 0.f), 1.f);
    float hm = 0.f;
    const size_t stride = (size_t)B_SZ * H_SZ;
    for (int t = 0; t < T_STEPS; ++t) {
        float v = Z[(size_t)t * stride + idx];
        hm = fmaxf(fmaf(be, hm, v), 0.f);
        S[(size_t)t * stride + idx] = (hm > 1.0f) ? 1 : 0;
    }
}

// ---------------------------------------------------------------------------
// GEMM2: one wave per row, W2 (40KB) in LDS, byte-spike input.
// IDENTICAL h-order and accumulation to the proven float version
// (s = 0.0/1.0 exactly) -> bit-identical z2. Reads 51MB instead of 205MB.
// ---------------------------------------------------------------------------
__global__ __launch_bounds__(256) void gemm2_kernel(
    const unsigned char* __restrict__ S, const float* __restrict__ W2,
    const float* __restrict__ b_ih2, const float* __restrict__ b_hh2,
    float* __restrict__ Z2)
{
    __shared__ float W2s[O_SZ * H_SZ];
    for (int i = threadIdx.x; i < O_SZ * H_SZ; i += blockDim.x)
        W2s[i] = W2[i];
    __syncthreads();

    const int wave  = threadIdx.x >> 6;
    const int lane  = threadIdx.x & 63;
    const int wgid  = blockIdx.x * (blockDim.x >> 6) + wave;
    const int nwave = gridDim.x * (blockDim.x >> 6);

    for (int m = wgid; m < M_ROWS; m += nwave) {
        const unsigned char* row = S + (size_t)m * H_SZ;
        float acc[O_SZ];
        #pragma unroll
        for (int o = 0; o < O_SZ; ++o) acc[o] = 0.f;

        for (int h = lane; h < H_SZ; h += 64) {
            float s = (float)row[h];
            #pragma unroll
            for (int o = 0; o < O_SZ; ++o)
                acc[o] = fmaf(s, W2s[o * H_SZ + h], acc[o]);
        }
        #pragma unroll
        for (int o = 0; o < O_SZ; ++o) {
            float v = acc[o];
            #pragma unroll
            for (int off = 32; off > 0; off >>= 1)
                v += __shfl_down(v, off, 64);
            if (lane == 0)
                Z2[(size_t)m * O_SZ + o] = v + b_ih2[o] + b_hh2[o];
        }
    }
}

// ---------------------------------------------------------------------------
// Scan2: in-place on d_out (thread-private read-then-write).
// ---------------------------------------------------------------------------
#define CH 20
__global__ __launch_bounds__(256) void scan2_kernel(
    float* __restrict__ Z2io, const float* __restrict__ beta2)
{
    int idx = blockIdx.x * blockDim.x + threadIdx.x;
    if (idx >= B_SZ * O_SZ) return;
    int o = idx % O_SZ;
    float be = fminf(fmaxf(beta2[o], 0.f), 1.f);
    float hm = 0.f;
    const int stride = B_SZ * O_SZ;
    for (int t0 = 0; t0 < T_STEPS; t0 += CH) {
        float v[CH];
        #pragma unroll
        for (int i = 0; i < CH; ++i)
            v[i] = Z2io[(size_t)(t0 + i) * stride + idx];
        #pragma unroll
        for (int i = 0; i < CH; ++i) {
            hm = fmaxf(fmaf(be, hm, v[i]), 0.f);
            Z2io[(size_t)(t0 + i) * stride + idx] = (hm > 1.0f) ? 1.0f : 0.0f;
        }
    }
}

// ---------------------------------------------------------------------------
extern "C" void kernel_launch(void* const* d_in, const int* in_sizes, int n_in,
                              void* d_out, int out_size, void* d_ws, size_t ws_size,
                              hipStream_t stream)
{
    const float* x     = (const float*)d_in[0];
    const float* W1    = (const float*)d_in[1];
    const float* bih1  = (const float*)d_in[2];
    const float* bhh1  = (const float*)d_in[3];
    const float* beta1 = (const float*)d_in[4];
    const float* W2    = (const float*)d_in[5];
    const float* bih2  = (const float*)d_in[6];
    const float* bhh2  = (const float*)d_in[7];
    const float* beta2 = (const float*)d_in[8];
    float* out = (float*)d_out;

    // z1 (204.8 MB) + Xp (163.84 MB) + Wp (3.28 MB) = 371.9 MB.
    // After gemm1, Xp is dead -> its region is reused for the byte-spike
    // buffer s1 (51.2 MB). Each graph replay rewrites Xp first (pack), so
    // no cross-call state dependence.
    char* base = (char*)d_ws;
    float* z1 = (float*)base;
    float* Xp = (float*)(base + (size_t)M_ROWS * H_SZ * 4);
    float* Wp = Xp + (size_t)MBLKS * KT * TILE_WORDS;
    unsigned char* s1 = (unsigned char*)Xp;

    pack_kernel<<<MBLKS * KT, 256, 0, stream>>>(x,  Xp, M_ROWS);
    pack_kernel<<<NBLKS * KT, 256, 0, stream>>>(W1, Wp, H_SZ);

    gemm1_v6<<<MBLKS * NBLKS, 256, 0, stream>>>(Xp, Wp, bih1, bhh1, z1);

    scan1_kernel<<<(B_SZ * H_SZ) / 256, 256, 0, stream>>>(z1, s1, beta1);
    gemm2_kernel<<<2048, 256, 0, stream>>>(s1, W2, bih2, bhh2, out);
    scan2_kernel<<<(B_SZ * O_SZ + 255) / 256, 256, 0, stream>>>(out, beta2);
}